// Round 5
// baseline (556.572 us; speedup 1.0000x reference)
//
#include <hip/hip_runtime.h>
#include <cstdint>
#include <cstddef>

// ====================================================================
// Attention block: out = softmax(mask? NEG : (QK^T*scale + bias)) V @ Wout^T
// B=8 L=1024 E=1024 H=16 A=64.
// float inputs -> const float*, bool mask -> const int*, output -> float*.
// Compute in bf16 MFMA. Workspace: Q,K,Vt,Vals bf16 = 67 MiB.
// k_attn: swapped QK^T (S^T layout); ALL four streams (K, V, bias, mask)
// register-prefetched one k-tile ahead (cross-iteration software pipeline)
// so no MFMA waits a fresh load. No barriers; per-wave LDS P transpose.
// ====================================================================

typedef __bf16 bf16;
typedef __attribute__((ext_vector_type(8))) __bf16 bf16x8;
typedef __attribute__((ext_vector_type(2))) __bf16 bf16x2;
typedef __attribute__((ext_vector_type(4))) float f32x4;
typedef __attribute__((ext_vector_type(4))) int i32x4;

#define MFMA_BF16(a, b, c) __builtin_amdgcn_mfma_f32_16x16x32_bf16(a, b, c, 0, 0, 0)

static constexpr float SCALE_ = 0.125f;                     // 64^-0.5
static constexpr float NEGF  = -3.4028234663852886e38f;     // finfo(f32).min (finite!)

__device__ __forceinline__ void gload_lds16(const bf16* g, bf16* l) {
  __builtin_amdgcn_global_load_lds((const __attribute__((address_space(1))) void*)g,
                                   (__attribute__((address_space(3))) void*)l,
                                   16, 0, 0);
}

__device__ __forceinline__ bf16x8 cvt8(const float* p) {
  f32x4 a = *(const f32x4*)p;
  f32x4 b = *(const f32x4*)(p + 4);
  bf16x8 r = {(bf16)a[0], (bf16)a[1], (bf16)a[2], (bf16)a[3],
              (bf16)b[0], (bf16)b[1], (bf16)b[2], (bf16)b[3]};
  return r;
}

// --------------------------------------------------------------------
// Kernel 1: QKV projection.  C[8192,3072] = X[8192,1024] @ W[3072,1024]^T
// --------------------------------------------------------------------
__global__ __launch_bounds__(256) void k_qkv(const float* __restrict__ X,
                                             const float* __restrict__ W,
                                             bf16* __restrict__ Q,
                                             bf16* __restrict__ Kc,
                                             bf16* __restrict__ Vt) {
  constexpr int K = 1024;
  __shared__ __align__(16) bf16 As[128 * 64];
  __shared__ __align__(16) bf16 Bs[128 * 64];
  const int t = threadIdx.x;
  const int lane = t & 63, w = t >> 6;
  const int wr = w >> 1, wc = w & 1;
  const int li = lane & 15, g = lane >> 4;
  const int m0 = (blockIdx.x & 63) * 128;   // 64 m-tiles
  const int n0 = (blockIdx.x >> 6) * 128;   // 24 n-tiles

  f32x4 acc[4][4] = {};

  for (int kt = 0; kt < K; kt += 64) {
#pragma unroll
    for (int it = 0; it < 4; ++it) {
      int c = it * 256 + t;               // 0..1023, 8 bf16 elems each
      int row = c >> 3, col = (c & 7) << 3;
      *(bf16x8*)(As + c * 8) = cvt8(X + (size_t)(m0 + row) * K + kt + col);
      *(bf16x8*)(Bs + c * 8) = cvt8(W + (size_t)(n0 + row) * K + kt + col);
    }
    __syncthreads();
#pragma unroll
    for (int kk = 0; kk < 2; ++kk) {
      bf16x8 af[4], bfr[4];
#pragma unroll
      for (int i = 0; i < 4; ++i)
        af[i] = *(const bf16x8*)(As + (wr * 64 + i * 16 + li) * 64 + kk * 32 + g * 8);
#pragma unroll
      for (int j = 0; j < 4; ++j)
        bfr[j] = *(const bf16x8*)(Bs + (wc * 64 + j * 16 + li) * 64 + kk * 32 + g * 8);
#pragma unroll
      for (int i = 0; i < 4; ++i)
#pragma unroll
        for (int j = 0; j < 4; ++j)
          acc[i][j] = MFMA_BF16(af[i], bfr[j], acc[i][j]);
    }
    __syncthreads();
  }

#pragma unroll
  for (int i = 0; i < 4; ++i) {
#pragma unroll
    for (int j = 0; j < 4; ++j) {
      int col = n0 + wc * 64 + j * 16 + li;
      int h = col / 192, r = col % 192;
#pragma unroll
      for (int rg = 0; rg < 4; ++rg) {
        int row = m0 + wr * 64 + i * 16 + g * 4 + rg;
        int b = row >> 10, l = row & 1023;
        bf16 v = (bf16)acc[i][j][rg];
        if (r < 64)
          Q[((size_t)((b * 16 + h) * 1024 + l)) * 64 + r] = v;
        else if (r < 128)
          Kc[((size_t)((b * 16 + h) * 1024 + l)) * 64 + (r - 64)] = v;
        else
          Vt[((size_t)((b * 16 + h) * 64 + (r - 128))) * 1024 + l] = v;
      }
    }
  }
}

// --------------------------------------------------------------------
// Kernel 2: flash attention. Grid 2048 x 256 threads; bh = lid%128 -> all
// 16 q-tiles of one head on one XCD. Per wave: 16 q rows, swapped QK^T:
//   s[kkf][rg] = S[q=q0+li][k = kkt + kkf*16 + g*4 + rg]
// Cross-iteration register pipeline: kreg/vreg/b4/m4 all hold tile t
// while tile t+1's loads are in flight (issue points spread through the
// tile so every load has >= half a tile of latency cover).
// --------------------------------------------------------------------
__global__ __launch_bounds__(256, 3) void k_attn(const bf16* __restrict__ Q,
                                                 const bf16* __restrict__ Kc,
                                                 const bf16* __restrict__ Vt,
                                                 const float* __restrict__ bias,
                                                 const int* __restrict__ mask,
                                                 bf16* __restrict__ Vals) {
  __shared__ __align__(16) bf16 Plds[4][2][16][72];  // per-wave, pad-72 rows
  const int t = threadIdx.x, lane = t & 63, w = t >> 6;
  const int li = lane & 15, g = lane >> 4;
  const int lid = blockIdx.x;
  const int bh = lid & 127;            // b*16+h; lid%8 == bh%8 -> same XCD
  const int qt = lid >> 7;
  const int b = bh >> 4, h = bh & 15;
  const int q0 = qt * 64 + w * 16;     // wave's 16 q rows

  const bf16* Qbase = Q + ((size_t)bh << 10) * 64;
  const bf16* Krow  = Kc + ((size_t)bh << 10) * 64 + (size_t)li * 64 + g * 8;
  const bf16* Vrow  = Vt + ((size_t)bh << 6) * 1024 + (size_t)li * 1024 + g * 8;
  const float* brow = bias + ((size_t)bh << 20) + (size_t)(q0 + li) * 1024 + g * 4;
  const int*   mrow = mask + ((size_t)bh << 20) + (size_t)(q0 + li) * 1024 + g * 4;

  bf16x8 qf[2];
#pragma unroll
  for (int c = 0; c < 2; ++c)
    qf[c] = *(const bf16x8*)(Qbase + (size_t)(q0 + li) * 64 + c * 32 + g * 8);

  f32x4 oacc[4] = {};
  float mrun = NEGF;
  float lrun = 0.f;

  // ---- pipeline registers (tile t resident while t+1 in flight) ----
  bf16x8 kreg[4][2];    // [kkf][c]: K[kkt+kkf*16+li][c*32+g*8..]
  bf16x8 vreg[4][2];    // [af][c] : Vt[af*16+li][kkt+c*32+g*8..]
  f32x4 b4[4];
  i32x4 m4[4];

  // ---- prologue: tile 0 loads ----
#pragma unroll
  for (int kkf = 0; kkf < 4; ++kkf) {
    b4[kkf] = *(const f32x4*)(brow + kkf * 16);
    m4[kkf] = *(const i32x4*)(mrow + kkf * 16);
#pragma unroll
    for (int c = 0; c < 2; ++c)
      kreg[kkf][c] = *(const bf16x8*)(Krow + (size_t)(kkf * 16) * 64 + c * 32);
  }
#pragma unroll
  for (int af = 0; af < 4; ++af)
#pragma unroll
    for (int c = 0; c < 2; ++c)
      vreg[af][c] = *(const bf16x8*)(Vrow + (size_t)(af * 16) * 1024 + c * 32);

  for (int kt6 = 0; kt6 < 16; ++kt6) {
    const int kkt = kt6 * 64;
    const int par = kt6 & 1;
    const bool more = (kt6 < 15);

    // ---- 1. S^T = K Q^T from preloaded kreg ----
    f32x4 s[4];
#pragma unroll
    for (int kkf = 0; kkf < 4; ++kkf) {
      f32x4 ss = {0.f, 0.f, 0.f, 0.f};
#pragma unroll
      for (int c = 0; c < 2; ++c) ss = MFMA_BF16(kreg[kkf][c], qf[c], ss);
      s[kkf] = ss;
    }

    // ---- 2. refill kreg for t+1 (hides under softmax+PV) ----
    if (more) {
#pragma unroll
      for (int kkf = 0; kkf < 4; ++kkf)
#pragma unroll
        for (int c = 0; c < 2; ++c)
          kreg[kkf][c] = *(const bf16x8*)(Krow + (size_t)(kkt + 64 + kkf * 16) * 64 + c * 32);
    }

    // ---- 3. scale + masked-bias (consumes b4/m4), tile max ----
    float tmax = NEGF;
#pragma unroll
    for (int kkf = 0; kkf < 4; ++kkf) {
#pragma unroll
      for (int rg = 0; rg < 4; ++rg) {
        float cv = m4[kkf][rg] ? NEGF : b4[kkf][rg];
        float sv = __builtin_fmaf(s[kkf][rg], SCALE_, cv);
        s[kkf][rg] = sv;
        tmax = fmaxf(tmax, sv);
      }
    }

    // ---- 4. refill b4/m4 for t+1 ----
    if (more) {
#pragma unroll
      for (int kkf = 0; kkf < 4; ++kkf) {
        b4[kkf] = *(const f32x4*)(brow + kkt + 64 + kkf * 16);
        m4[kkf] = *(const i32x4*)(mrow + kkt + 64 + kkf * 16);
      }
    }

    // ---- 5. softmax update + P -> LDS ----
    tmax = fmaxf(tmax, __shfl_xor(tmax, 16));
    tmax = fmaxf(tmax, __shfl_xor(tmax, 32));
    float mnew = fmaxf(mrun, tmax);
    float corr = __expf(mrun - mnew);   // NEG-NEG=0 -> 1; NEG-real -> 0
    float psum = 0.f;
#pragma unroll
    for (int kkf = 0; kkf < 4; ++kkf) {
      float p0 = __expf(s[kkf][0] - mnew);
      float p1 = __expf(s[kkf][1] - mnew);
      float p2 = __expf(s[kkf][2] - mnew);
      float p3 = __expf(s[kkf][3] - mnew);
      psum += (p0 + p1) + (p2 + p3);
      bf16x2 pa = {(bf16)p0, (bf16)p1};
      bf16x2 pb = {(bf16)p2, (bf16)p3};
      *(bf16x2*)(&Plds[w][par][li][kkf * 16 + g * 4])     = pa;
      *(bf16x2*)(&Plds[w][par][li][kkf * 16 + g * 4 + 2]) = pb;
    }
    psum += __shfl_xor(psum, 16);
    psum += __shfl_xor(psum, 32);
    lrun = lrun * corr + psum;
    mrun = mnew;

    // ---- 6. rescale O ----
    float cq[4];
#pragma unroll
    for (int rg = 0; rg < 4; ++rg) cq[rg] = __shfl(corr, g * 4 + rg);
#pragma unroll
    for (int af = 0; af < 4; ++af)
#pragma unroll
      for (int rg = 0; rg < 4; ++rg) oacc[af][rg] *= cq[rg];

    // ---- 7. O += P V from preloaded vreg ----
#pragma unroll
    for (int c = 0; c < 2; ++c) {
      bf16x8 pf = *(const bf16x8*)(&Plds[w][par][li][c * 32 + g * 8]);
#pragma unroll
      for (int af = 0; af < 4; ++af)
        oacc[af] = MFMA_BF16(pf, vreg[af][c], oacc[af]);
    }

    // ---- 8. refill vreg for t+1 (full tile of latency cover) ----
    if (more) {
#pragma unroll
      for (int af = 0; af < 4; ++af)
#pragma unroll
        for (int c = 0; c < 2; ++c)
          vreg[af][c] = *(const bf16x8*)(Vrow + (size_t)(af * 16) * 1024 + kkt + 64 + c * 32);
    }
  }

  float linv[4];
#pragma unroll
  for (int rg = 0; rg < 4; ++rg) linv[rg] = 1.0f / __shfl(lrun, g * 4 + rg);
#pragma unroll
  for (int af = 0; af < 4; ++af) {
#pragma unroll
    for (int rg = 0; rg < 4; ++rg) {
      int q = q0 + g * 4 + rg;
      int col = h * 64 + af * 16 + li;
      Vals[(((size_t)(b * 1024 + q)) << 10) + col] = (bf16)(oacc[af][rg] * linv[rg]);
    }
  }
}

// --------------------------------------------------------------------
// Kernel 3: output projection. out[8192,1024] = Vals @ Wout[1024,1024]^T
// --------------------------------------------------------------------
__global__ __launch_bounds__(256) void k_out(const bf16* __restrict__ X,
                                             const float* __restrict__ W,
                                             float* __restrict__ Out) {
  constexpr int K = 1024;
  __shared__ __align__(16) bf16 As[128 * 64];
  __shared__ __align__(16) bf16 Bs[128 * 64];
  const int t = threadIdx.x;
  const int lane = t & 63, w = t >> 6;
  const int wr = w >> 1, wc = w & 1;
  const int li = lane & 15, g = lane >> 4;
  const int m0 = (blockIdx.x & 63) * 128;   // 64 m-tiles
  const int n0 = (blockIdx.x >> 6) * 128;   // 8 n-tiles

  f32x4 acc[4][4] = {};

  for (int kt = 0; kt < K; kt += 64) {
#pragma unroll
    for (int it = 0; it < 4; ++it) {
      int c = it * 256 + t;
      int row = c >> 3, col = (c & 7) << 3;
      gload_lds16(X + (size_t)(m0 + row) * K + kt + col, As + c * 8);
      *(bf16x8*)(Bs + c * 8) = cvt8(W + (size_t)(n0 + row) * K + kt + col);
    }
    __syncthreads();
#pragma unroll
    for (int kk = 0; kk < 2; ++kk) {
      bf16x8 af[4], bfr[4];
#pragma unroll
      for (int i = 0; i < 4; ++i)
        af[i] = *(const bf16x8*)(As + (wr * 64 + i * 16 + li) * 64 + kk * 32 + g * 8);
#pragma unroll
      for (int j = 0; j < 4; ++j)
        bfr[j] = *(const bf16x8*)(Bs + (wc * 64 + j * 16 + li) * 64 + kk * 32 + g * 8);
#pragma unroll
      for (int i = 0; i < 4; ++i)
#pragma unroll
        for (int j = 0; j < 4; ++j)
          acc[i][j] = MFMA_BF16(af[i], bfr[j], acc[i][j]);
    }
    __syncthreads();
  }

#pragma unroll
  for (int i = 0; i < 4; ++i) {
#pragma unroll
    for (int j = 0; j < 4; ++j) {
      int col = n0 + wc * 64 + j * 16 + li;
#pragma unroll
      for (int rg = 0; rg < 4; ++rg) {
        int row = m0 + wr * 64 + i * 16 + g * 4 + rg;
        Out[((size_t)row << 10) + col] = acc[i][j][rg];
      }
    }
  }
}

// --------------------------------------------------------------------
extern "C" void kernel_launch(void* const* d_in, const int* in_sizes, int n_in,
                              void* d_out, int out_size, void* d_ws, size_t ws_size,
                              hipStream_t stream) {
  const float* emb  = (const float*)d_in[0];
  const int*   mask = (const int*)d_in[1];
  const float* bias = (const float*)d_in[2];
  const float* Wqkv = (const float*)d_in[3];
  const float* Wout = (const float*)d_in[4];
  float* out = (float*)d_out;

  const size_t HEADS_ELEMS = (size_t)8 * 16 * 1024 * 64;  // 8.39M elems
  bf16* Q    = (bf16*)d_ws;
  bf16* Kc   = Q + HEADS_ELEMS;
  bf16* Vt   = Kc + HEADS_ELEMS;
  bf16* Vals = Vt + HEADS_ELEMS;   // total ~67 MiB of ws

  k_qkv<<<dim3(64 * 24), 256, 0, stream>>>(emb, Wqkv, Q, Kc, Vt);
  k_attn<<<dim3(2048), 256, 0, stream>>>(Q, Kc, Vt, bias, mask, Vals);
  k_out<<<dim3(64 * 8), 256, 0, stream>>>(Vals, Wout, out);
}